// Round 8
// baseline (472.150 us; speedup 1.0000x reference)
//
#include <hip/hip_runtime.h>
#include <math.h>

// Problem shape (fixed): B=2, C=256, H=W=64 -> N=4096, d=64, K=32, M=256, topk=8
#define QOFF 32
#define KOFF 96
#define VOFF 160
#define NSUB 8

// (v desc, idx asc) total order — matches lax.top_k tie-breaking
#define GTPAIR(va,ia,vb,ib) (((va) > (vb)) || ((va) == (vb) && (ia) < (ib)))
#define CE8(va,ia,vb,ib) { const bool c_ = GTPAIR(va,ia,vb,ib); \
    const float hv_ = c_?(va):(vb), lv_ = c_?(vb):(va); \
    const int   hi_ = c_?(ia):(ib), li_ = c_?(ib):(ia); \
    (va)=hv_; (ia)=hi_; (vb)=lv_; (ib)=li_; }
#define SELMAXP(wv,wi,va,ia,vb,ib) { const bool c_ = GTPAIR(va,ia,vb,ib); \
    (wv) = c_?(va):(vb); (wi) = c_?(ia):(ib); }

// ============================================================================
// Kernel A: fused projection GEMM.  Y[b][n][0..415] = {sem_logits(32), q(64),
// k(64), v(256)} ; Y row-major position rows of 416 floats.
// ============================================================================
__global__ __launch_bounds__(256) void proj_kernel(
    const float* __restrict__ x,
    const float* __restrict__ sem_w, const float* __restrict__ sem_b,
    const float* __restrict__ q_w, const float* __restrict__ k_w,
    const float* __restrict__ v_w, float* __restrict__ Y)
{
    const int t = threadIdx.x;
    const int n0 = blockIdx.x * 64;
    const int oc0 = blockIdx.y * 64;
    const int b = blockIdx.z;
    const int ty = t >> 4, tx = t & 15;

    __shared__ float As[16][68];
    __shared__ float Bs[16][64];

    float acc[4][4];
#pragma unroll
    for (int i = 0; i < 4; i++)
#pragma unroll
        for (int j = 0; j < 4; j++) acc[i][j] = 0.f;

    const int oc_l = t >> 2;
    const int cp = t & 3;
    const int oc_g = oc0 + oc_l;
    const float* wrow = nullptr;
    if (oc_g < 32) wrow = sem_w + oc_g * 256;
    else if (oc_g < 96) wrow = q_w + (oc_g - 32) * 256;
    else if (oc_g < 160) wrow = k_w + (oc_g - 96) * 256;
    else if (oc_g < 416) wrow = v_w + (oc_g - 160) * 256;

    const int bk = t >> 4;
    const int bn = (t & 15) << 2;

    for (int c0 = 0; c0 < 256; c0 += 16) {
        __syncthreads();
        float4 w4 = make_float4(0.f, 0.f, 0.f, 0.f);
        if (wrow) w4 = *(const float4*)(wrow + c0 + (cp << 2));
        As[(cp << 2) + 0][oc_l] = w4.x;
        As[(cp << 2) + 1][oc_l] = w4.y;
        As[(cp << 2) + 2][oc_l] = w4.z;
        As[(cp << 2) + 3][oc_l] = w4.w;
        *(float4*)&Bs[bk][bn] =
            *(const float4*)(x + ((size_t)(b * 256 + c0 + bk)) * 4096 + n0 + bn);
        __syncthreads();
#pragma unroll
        for (int kk = 0; kk < 16; kk++) {
            float4 a4 = *(float4*)&As[kk][ty << 2];
            float4 b4 = *(float4*)&Bs[kk][tx << 2];
            acc[0][0] += a4.x * b4.x; acc[0][1] += a4.x * b4.y;
            acc[0][2] += a4.x * b4.z; acc[0][3] += a4.x * b4.w;
            acc[1][0] += a4.y * b4.x; acc[1][1] += a4.y * b4.y;
            acc[1][2] += a4.y * b4.z; acc[1][3] += a4.y * b4.w;
            acc[2][0] += a4.z * b4.x; acc[2][1] += a4.z * b4.y;
            acc[2][2] += a4.z * b4.z; acc[2][3] += a4.z * b4.w;
            acc[3][0] += a4.w * b4.x; acc[3][1] += a4.w * b4.y;
            acc[3][2] += a4.w * b4.z; acc[3][3] += a4.w * b4.w;
        }
    }

    if (oc0 + (ty << 2) < 416) {
        float bias[4];
#pragma unroll
        for (int i = 0; i < 4; i++) {
            int oc = oc0 + (ty << 2) + i;
            bias[i] = (oc < 32) ? sem_b[oc] : 0.f;
        }
#pragma unroll
        for (int j = 0; j < 4; j++) {
            int n = n0 + (tx << 2) + j;
            float4 o4 = make_float4(acc[0][j] + bias[0], acc[1][j] + bias[1],
                                    acc[2][j] + bias[2], acc[3][j] + bias[3]);
            *(float4*)(Y + ((size_t)(b * 4096 + n)) * 416 + oc0 + (ty << 2)) = o4;
        }
    }
}

// ============================================================================
// Kernel B: per-position softmax over the 32 sem logits (in place) + argmax.
// ============================================================================
__global__ __launch_bounds__(256) void semsoft_kernel(float* __restrict__ Y,
                                                      int* __restrict__ hr)
{
    const int g = blockIdx.x * 256 + threadIdx.x;
    float* row = Y + (size_t)g * 416;
    float v[32];
#pragma unroll
    for (int i = 0; i < 8; i++) *(float4*)&v[i * 4] = *(float4*)&row[i * 4];
    float mx = v[0]; int am = 0;
#pragma unroll
    for (int kk = 1; kk < 32; kk++) if (v[kk] > mx) { mx = v[kk]; am = kk; }
    float s = 0.f;
#pragma unroll
    for (int kk = 0; kk < 32; kk++) { v[kk] = expf(v[kk] - mx); s += v[kk]; }
    const float inv = 1.f / s;
#pragma unroll
    for (int kk = 0; kk < 32; kk++) v[kk] *= inv;
#pragma unroll
    for (int i = 0; i < 8; i++) *(float4*)&row[i * 4] = *(float4*)&v[i * 4];
    hr[g] = am;
}

// ============================================================================
// Kernel B2: bin positions by hard region.  cnt must be pre-zeroed.
// ============================================================================
__global__ __launch_bounds__(256) void bin_kernel(
    const int* __restrict__ hr, int* __restrict__ cnt, int* __restrict__ plist)
{
    const int g = blockIdx.x * 256 + threadIdx.x;   // b*4096+n
    const int b = g >> 12, n = g & 4095;
    const int r = hr[g];
    const int slot = atomicAdd(&cnt[b * 32 + r], 1);
    plist[((size_t)(b * 32 + r)) * 4096 + slot] = n;
}

// ============================================================================
// Kernel C: region_k/v partials as a tiled GEMM.
// ============================================================================
__global__ __launch_bounds__(256) void region_partial_kernel(
    const float* __restrict__ Y, float* __restrict__ P)
{
    const int ch = blockIdx.x;     // 0..31 (position chunk of 128)
    const int b  = blockIdx.y;     // 0..1
    const int dg = blockIdx.z;     // 0..4  (dd group of 64)
    const int t = threadIdx.x;
    __shared__ float sem_s[16][33];
    __shared__ float kv_s[16][68];
    const int kg = t >> 4;
    const int dq = t & 15;
    float acc[2][4];
#pragma unroll
    for (int i = 0; i < 2; i++)
#pragma unroll
        for (int j = 0; j < 4; j++) acc[i][j] = 0.f;

    const size_t gbase = (size_t)(b * 4096 + ch * 128);
    const int sr = t >> 4, sc = (t & 15) << 2;
    for (int r0 = 0; r0 < 128; r0 += 16) {
        __syncthreads();
        {
            sem_s[t >> 5][t & 31] = Y[(gbase + r0 + (t >> 5)) * 416 + (t & 31)];
            const int i2 = t + 256;
            sem_s[i2 >> 5][i2 & 31] = Y[(gbase + r0 + (i2 >> 5)) * 416 + (i2 & 31)];
        }
        {
            *(float4*)&kv_s[sr][sc] =
                *(const float4*)(Y + (gbase + r0 + sr) * 416 + 96 + dg * 64 + sc);
        }
        __syncthreads();
#pragma unroll
        for (int r = 0; r < 16; r++) {
            const float s0 = sem_s[r][(kg << 1) + 0];
            const float s1 = sem_s[r][(kg << 1) + 1];
            const float4 kv = *(float4*)&kv_s[r][dq << 2];
            acc[0][0] += s0 * kv.x; acc[0][1] += s0 * kv.y;
            acc[0][2] += s0 * kv.z; acc[0][3] += s0 * kv.w;
            acc[1][0] += s1 * kv.x; acc[1][1] += s1 * kv.y;
            acc[1][2] += s1 * kv.z; acc[1][3] += s1 * kv.w;
        }
    }
    float* Pb = P + ((size_t)(b * 32 + ch)) * 10240 + dg * 64;
#pragma unroll
    for (int i = 0; i < 2; i++)
        *(float4*)&Pb[((kg << 1) + i) * 320 + (dq << 2)] =
            make_float4(acc[i][0], acc[i][1], acc[i][2], acc[i][3]);
}

__global__ __launch_bounds__(256) void region_reduce_kernel(
    const float* __restrict__ P, float* __restrict__ region)
{
    const int idx = blockIdx.x * 256 + threadIdx.x;
    if (idx >= 2 * 10240) return;
    const int b = idx / 10240, rem = idx - b * 10240;
    float s = 0.f;
    for (int ch = 0; ch < 32; ch++)
        s += P[((size_t)(b * 32 + ch)) * 10240 + rem];
    region[(size_t)b * 10240 + rem] = s;
}

// ============================================================================
// Kernel D: top-256 indices of sem[b][k][:] over N=4096 (set semantics).
// ============================================================================
__global__ __launch_bounds__(256) void topk_sem_kernel(
    const float* __restrict__ Y, int* __restrict__ ti)
{
    const int kreg = blockIdx.x, b = blockIdx.y;
    const int t = threadIdx.x;
    __shared__ int wpart[4];
    __shared__ int sh_eq[256];
    __shared__ int ctr;

    unsigned int uv[16];
    const int nbase = t * 16;
#pragma unroll
    for (int i = 0; i < 16; i++) {
        float v = Y[((size_t)(b * 4096 + nbase + i)) * 416 + kreg];
        unsigned int u = __float_as_uint(v);
        uv[i] = (u & 0x80000000u) ? ~u : (u | 0x80000000u);
    }
    unsigned long long lo = 0ull, hi = 0xFFFFFFFFull;
    while (lo < hi) {
        const unsigned int mid = (unsigned int)((lo + hi + 1ull) >> 1);
        int c = 0;
#pragma unroll
        for (int i = 0; i < 16; i++) c += (uv[i] >= mid) ? 1 : 0;
#pragma unroll
        for (int off = 1; off < 64; off <<= 1) c += __shfl_xor(c, off);
        __syncthreads();
        if ((t & 63) == 0) wpart[t >> 6] = c;
        __syncthreads();
        const int tot = wpart[0] + wpart[1] + wpart[2] + wpart[3];
        if (tot >= 256) lo = mid; else hi = (unsigned long long)mid - 1ull;
    }
    const unsigned int T = (unsigned int)lo;
    int cgt = 0, ceq = 0;
#pragma unroll
    for (int i = 0; i < 16; i++) { cgt += (uv[i] > T) ? 1 : 0; ceq += (uv[i] == T) ? 1 : 0; }
    int cg = cgt;
#pragma unroll
    for (int off = 1; off < 64; off <<= 1) cg += __shfl_xor(cg, off);
    __syncthreads();
    if ((t & 63) == 0) wpart[t >> 6] = cg;
    sh_eq[t] = ceq;
    if (t == 0) ctr = 0;
    __syncthreads();
    const int c1 = wpart[0] + wpart[1] + wpart[2] + wpart[3];
    int eqbase = 0;
    for (int i = 0; i < t; i++) eqbase += sh_eq[i];
    int* outp = ti + ((size_t)(b * 32 + kreg)) * 256;
    int seen = 0;
#pragma unroll
    for (int i = 0; i < 16; i++) {
        if (uv[i] > T) {
            int pos = atomicAdd(&ctr, 1);
            outp[pos] = nbase + i;
        } else if (uv[i] == T) {
            int r = eqbase + seen; seen++;
            if (c1 + r < 256) outp[c1 + r] = nbase + i;
        }
    }
}

// ============================================================================
// Kernel E: region-grouped sparse attention. Pool K staged once per block.
// Top-8 via per-lane sort-4 + 6-level bitonic shfl merge (register-only,
// static scalar names; merge loop kept rolled to bound code size).
// ============================================================================
__global__ __launch_bounds__(256) void sparse_attn_kernel(
    const float* __restrict__ Y, const int* __restrict__ cnt,
    const int* __restrict__ plist, const int* __restrict__ ti,
    float* __restrict__ sp)
{
    const int rb = blockIdx.x;          // b*32+region
    const int sub = blockIdx.y;         // 0..NSUB-1
    const int b = rb >> 5;
    const int t = threadIdx.x, wid = t >> 6, lane = t & 63;

    int count = cnt[rb];
    count = min(max(count, 0), 4096);   // clamp: profiling-replay / poison safety
    const int chunk = (count + NSUB - 1) / NSUB;
    const int p0 = sub * chunk;
    const int p1 = min(p0 + chunk, count);
    if (p1 <= p0) return;
    const int npass = (p1 - p0 + 15) >> 4;

    __shared__ int pool_s[256];          // 1 KB
    __shared__ float K_sT[64][256];      // 64 KB  [j][key]
    __shared__ float q_sT[4][64][4];     // 4 KB   [wid][j][pos]

    if (t < 64)
        *(int4*)&pool_s[t << 2] = *(const int4*)(ti + (size_t)rb * 256 + (t << 2));
    __syncthreads();
    {   // stage ALL 256 keys: 2 threads per key, 32 floats each, 2 halves
        const int krow = t >> 1, jh = t & 1;
#pragma unroll
        for (int hh = 0; hh < 2; hh++) {
            const int key = (hh << 7) + krow;
            const int kidx = pool_s[key];
            const float* kr = Y + ((size_t)((b << 12) + kidx)) * 416 + KOFF + (jh << 5);
#pragma unroll
            for (int jj = 0; jj < 8; jj++) {
                float4 kv = *(const float4*)(kr + (jj << 2));
                const int jb = (jh << 5) + (jj << 2);
                K_sT[jb + 0][key] = kv.x;
                K_sT[jb + 1][key] = kv.y;
                K_sT[jb + 2][key] = kv.z;
                K_sT[jb + 3][key] = kv.w;
            }
        }
    }
    __syncthreads();

    const float inv_scale = 1.0f / (8.0f + 1e-6f);
    const int* myplist = plist + (size_t)rb * 4096;

    for (int pass = 0; pass < npass; pass++) {
        int gg[4]; bool val[4];
#pragma unroll
        for (int p = 0; p < 4; p++) {
            const int idx = p0 + (pass << 4) + (wid << 2) + p;
            val[p] = (idx < p1);            // uniform across the wave
            const int n = myplist[val[p] ? idx : p0];
            gg[p] = (b << 12) + n;
            q_sT[wid][lane][p] = Y[(size_t)gg[p] * 416 + QOFF + lane];
        }
        // all lanes' q writes drained before cross-lane reads (same wave)
        asm volatile("s_waitcnt lgkmcnt(0)" ::: "memory");

        // sims: lane owns keys {2l, 2l+1, 128+2l, 128+2l+1} for 4 positions
        float a[4][4];
#pragma unroll
        for (int p = 0; p < 4; p++)
#pragma unroll
            for (int sl = 0; sl < 4; sl++) a[p][sl] = 0.f;
#pragma unroll
        for (int j = 0; j < 64; j++) {
            const float2 k0 = *(const float2*)&K_sT[j][lane << 1];
            const float2 k1 = *(const float2*)&K_sT[j][128 + (lane << 1)];
            const float4 q4 = *(const float4*)&q_sT[wid][j][0];
            a[0][0] += q4.x * k0.x; a[0][1] += q4.x * k0.y;
            a[0][2] += q4.x * k1.x; a[0][3] += q4.x * k1.y;
            a[1][0] += q4.y * k0.x; a[1][1] += q4.y * k0.y;
            a[1][2] += q4.y * k1.x; a[1][3] += q4.y * k1.y;
            a[2][0] += q4.z * k0.x; a[2][1] += q4.z * k0.y;
            a[2][2] += q4.z * k1.x; a[2][3] += q4.z * k1.y;
            a[3][0] += q4.w * k0.x; a[3][1] += q4.w * k0.y;
            a[3][2] += q4.w * k1.x; a[3][3] += q4.w * k1.y;
        }

#pragma unroll
        for (int p = 0; p < 4; p++) {
            if (!val[p]) continue;          // wave-uniform branch; shfls safe
            const int m0 = lane << 1;
            // per-lane sorted-4 (desc by value, asc by index on ties)
            float A0 = a[p][0] * inv_scale; int E0 = m0;
            float A1 = a[p][1] * inv_scale; int E1 = m0 + 1;
            float A2 = a[p][2] * inv_scale; int E2 = 128 + m0;
            float A3 = a[p][3] * inv_scale; int E3 = 128 + m0 + 1;
            CE8(A0,E0,A1,E1); CE8(A2,E2,A3,E3);
            CE8(A0,E0,A2,E2); CE8(A1,E1,A3,E3); CE8(A1,E1,A2,E2);
            float A4 = -3e38f, A5 = -3e38f, A6 = -3e38f, A7 = -3e38f;
            int E4 = 2147483647, E5 = 2147483647, E6 = 2147483647, E7 = 2147483647;

            // 6 merge levels; kept rolled (runtime shfl offset) to bound
            // code size — registers are named scalars, no scratch.
#pragma unroll 1
            for (int off = 1; off < 64; off <<= 1) {
                const float B0 = __shfl_xor(A0, off), B1 = __shfl_xor(A1, off);
                const float B2 = __shfl_xor(A2, off), B3 = __shfl_xor(A3, off);
                const float B4 = __shfl_xor(A4, off), B5 = __shfl_xor(A5, off);
                const float B6 = __shfl_xor(A6, off), B7 = __shfl_xor(A7, off);
                const int F0 = __shfl_xor(E0, off), F1 = __shfl_xor(E1, off);
                const int F2 = __shfl_xor(E2, off), F3 = __shfl_xor(E3, off);
                const int F4 = __shfl_xor(E4, off), F5 = __shfl_xor(E5, off);
                const int F6 = __shfl_xor(E6, off), F7 = __shfl_xor(E7, off);
                // half-cleaner: W[i] = maxpair(A[i], B[7-i])
                float W0,W1,W2,W3,W4,W5,W6,W7; int G0,G1,G2,G3,G4,G5,G6,G7;
                SELMAXP(W0,G0, A0,E0, B7,F7);
                SELMAXP(W1,G1, A1,E1, B6,F6);
                SELMAXP(W2,G2, A2,E2, B5,F5);
                SELMAXP(W3,G3, A3,E3, B4,F4);
                SELMAXP(W4,G4, A4,E4, B3,F3);
                SELMAXP(W5,G5, A5,E5, B2,F2);
                SELMAXP(W6,G6, A6,E6, B1,F1);
                SELMAXP(W7,G7, A7,E7, B0,F0);
                // bitonic merge desc: dist 4, 2, 1
                CE8(W0,G0,W4,G4); CE8(W1,G1,W5,G5);
                CE8(W2,G2,W6,G6); CE8(W3,G3,W7,G7);
                CE8(W0,G0,W2,G2); CE8(W1,G1,W3,G3);
                CE8(W4,G4,W6,G6); CE8(W5,G5,W7,G7);
                CE8(W0,G0,W1,G1); CE8(W2,G2,W3,G3);
                CE8(W4,G4,W5,G5); CE8(W6,G6,W7,G7);
                A0=W0;E0=G0; A1=W1;E1=G1; A2=W2;E2=G2; A3=W3;E3=G3;
                A4=W4;E4=G4; A5=W5;E5=G5; A6=W6;E6=G6; A7=W7;E7=G7;
            }

            // softmax over the 8 (A0 is the max) + V gather
            const float w0 = 1.f,            w1 = expf(A1 - A0);
            const float w2 = expf(A2 - A0), w3 = expf(A3 - A0);
            const float w4 = expf(A4 - A0), w5 = expf(A5 - A0);
            const float w6 = expf(A6 - A0), w7 = expf(A7 - A0);
            const float inv = 1.f / (w0 + w1 + w2 + w3 + w4 + w5 + w6 + w7);
            float4 acc = make_float4(0.f, 0.f, 0.f, 0.f);
            {
                const float ww[8] = {w0,w1,w2,w3,w4,w5,w6,w7};
                const int   ee[8] = {E0,E1,E2,E3,E4,E5,E6,E7};
#pragma unroll
                for (int j = 0; j < 8; j++) {
                    const int actual = pool_s[ee[j]];
                    const float4 vv = *(const float4*)(
                        Y + ((size_t)((b << 12) + actual)) * 416 + VOFF + (lane << 2));
                    const float w = ww[j] * inv;
                    acc.x += w * vv.x; acc.y += w * vv.y;
                    acc.z += w * vv.z; acc.w += w * vv.w;
                }
            }
            *(float4*)(sp + (size_t)gg[p] * 256 + (lane << 2)) = acc;
        }
    }
}

// ============================================================================
// Kernel F: dense region-attention branch + combine (in place over sp).
// ============================================================================
__global__ __launch_bounds__(256) void combine_kernel(
    const float* __restrict__ Y, const float* __restrict__ region,
    const float* __restrict__ alpha, float* __restrict__ sp)
{
    const int t = threadIdx.x, wid = t >> 6, lane = t & 63;
    const int b = blockIdx.y;
    const int n0 = blockIdx.x << 5;
    __shared__ float rk_s[32][65];
    __shared__ float rv_s[32][256];
    __shared__ float q_all[32][64];

    const float* reg = region + (size_t)b * 10240;
    for (int idx = t; idx < 10240; idx += 256) {
        const int kk = idx / 320, dd = idx - kk * 320;
        const float v = reg[idx];
        if (dd < 64) rk_s[kk][dd] = v; else rv_s[kk][dd - 64] = v;
    }
    const size_t g0 = (size_t)(b << 12) + n0;
    for (int idx = t; idx < 2048; idx += 256)
        q_all[idx >> 6][idx & 63] = Y[(g0 + (idx >> 6)) * 416 + QOFF + (idx & 63)];
    __syncthreads();

    const float asig = 1.f / (1.f + expf(-alpha[0]));
    const float inv_scale = 1.0f / (8.0f + 1e-6f);
    const int kk = lane & 31, half = lane >> 5;

    for (int pp = 0; pp < 8; pp++) {
        const int n_l = (wid << 3) + pp;
        const size_t g = g0 + n_l;
        float part = 0.f;
        {
            const float* qr = &q_all[n_l][half << 5];
            const float* rkr = &rk_s[kk][half << 5];
#pragma unroll
            for (int j = 0; j < 32; j++) part += qr[j] * rkr[j];
        }
        part += __shfl_xor(part, 32);
        const float logit = part * inv_scale;
        float mx = logit;
#pragma unroll
        for (int off = 1; off < 32; off <<= 1) mx = fmaxf(mx, __shfl_xor(mx, off));
        const float e = expf(logit - mx);
        float s = e;
#pragma unroll
        for (int off = 1; off < 32; off <<= 1) s += __shfl_xor(s, off);
        const float w_own = e / s;

        float4 acc = make_float4(0.f, 0.f, 0.f, 0.f);
#pragma unroll
        for (int k2 = 0; k2 < 32; k2++) {
            const float w = __shfl(w_own, k2);
            const float4 rv = *(const float4*)&rv_s[k2][lane << 2];
            acc.x += w * rv.x; acc.y += w * rv.y;
            acc.z += w * rv.z; acc.w += w * rv.w;
        }
        float* spr = sp + g * 256 + (lane << 2);
        float4 spv = *(float4*)spr;
        float4 o;
        o.x = asig * acc.x + (1.f - asig) * spv.x;
        o.y = asig * acc.y + (1.f - asig) * spv.y;
        o.z = asig * acc.z + (1.f - asig) * spv.z;
        o.w = asig * acc.w + (1.f - asig) * spv.w;
        *(float4*)spr = o;
    }
}

// ============================================================================
// Kernel G: fused = fuse_w @ combined + fuse_b ; out = x + fused ; channel LN.
// ============================================================================
__global__ __launch_bounds__(256) void fuse_ln_kernel(
    const float* __restrict__ comb, const float* __restrict__ fuse_w,
    const float* __restrict__ fuse_b, const float* __restrict__ x,
    const float* __restrict__ ln_g, const float* __restrict__ ln_b,
    float* __restrict__ out)
{
    const int t = threadIdx.x;
    const int n0 = blockIdx.x << 5;
    const int b = blockIdx.y;

    __shared__ float smem[32 * 256 + 32 * 36];
    float (*Ws)[256] = (float (*)[256])smem;
    float (*cs)[36] = (float (*)[36])(smem + 32 * 256);
    float (*Fs)[260] = (float (*)[260])smem;
    __shared__ float red1[8][32], red2[8][32];
    __shared__ float mu_s[32], rs_s[32];

    const int og = t & 63;
    const int ng = t >> 6;
    float acc[4][8];
#pragma unroll
    for (int i = 0; i < 4; i++)
#pragma unroll
        for (int j = 0; j < 8; j++) acc[i][j] = 0.f;

    const int cl = (t << 2) & 31;
    const int nl = t >> 3;

    for (int c0 = 0; c0 < 256; c0 += 32) {
        __syncthreads();
        {
            const float* wr = fuse_w + (size_t)t * 256 + c0;
#pragma unroll
            for (int j = 0; j < 8; j++) {
                float4 w4 = *(const float4*)(wr + (j << 2));
                Ws[(j << 2) + 0][t] = w4.x;
                Ws[(j << 2) + 1][t] = w4.y;
                Ws[(j << 2) + 2][t] = w4.z;
                Ws[(j << 2) + 3][t] = w4.w;
            }
        }
        {
            float4 c4 = *(const float4*)(
                comb + ((size_t)(b * 4096 + n0 + nl)) * 256 + c0 + cl);
            cs[cl + 0][nl] = c4.x;
            cs[cl + 1][nl] = c4.y;
            cs[cl + 2][nl] = c4.z;
            cs[cl + 3][nl] = c4.w;
        }
        __syncthreads();
#pragma unroll
        for (int cc = 0; cc < 32; cc++) {
            float4 w4 = *(float4*)&Ws[cc][og << 2];
            float4 ca = *(float4*)&cs[cc][ng << 3];
            float4 cb = *(float4*)&cs[cc][(ng << 3) + 4];
            float wv[4] = {w4.x, w4.y, w4.z, w4.w};
            float cv[8] = {ca.x, ca.y, ca.z, ca.w, cb.x, cb.y, cb.z, cb.w};
#pragma unroll
            for (int i = 0; i < 4; i++)
#pragma unroll
                for (int j = 0; j < 8; j++) acc[i][j] += wv[i] * cv[j];
        }
    }

    __syncthreads();
#pragma unroll
    for (int i = 0; i < 4; i++) {
        const int o = (og << 2) + i;
        const float fb = fuse_b[o];
        const float* xr = x + ((size_t)(b * 256 + o)) * 4096 + n0 + (ng << 3);
        float4 xa = *(const float4*)xr;
        float4 xb = *(const float4*)(xr + 4);
        float xv[8] = {xa.x, xa.y, xa.z, xa.w, xb.x, xb.y, xb.z, xb.w};
#pragma unroll
        for (int j = 0; j < 8; j++)
            Fs[(ng << 3) + j][o] = acc[i][j] + fb + xv[j];
    }
    __syncthreads();
    {
        const int n = t & 31, part = t >> 5;
        float s1 = 0.f, s2 = 0.f;
#pragma unroll
        for (int i = 0; i < 32; i++) {
            const float v = Fs[n][(part << 5) + i];
            s1 += v; s2 += v * v;
        }
        red1[part][n] = s1; red2[part][n] = s2;
    }
    __syncthreads();
    if (t < 32) {
        float s1 = 0.f, s2 = 0.f;
#pragma unroll
        for (int p = 0; p < 8; p++) { s1 += red1[p][t]; s2 += red2[p][t]; }
        const float mean = s1 * (1.f / 256.f);
        const float var = s2 * (1.f / 256.f) - mean * mean;
        mu_s[t] = mean;
        rs_s[t] = rsqrtf(var + 1e-5f);
    }
    __syncthreads();
#pragma unroll
    for (int j = 0; j < 32; j++) {
        const int idx = (j << 8) + t;
        const int o = idx >> 5, n = idx & 31;
        const float v = (Fs[n][o] - mu_s[n]) * rs_s[n] * ln_g[o] + ln_b[o];
        out[((size_t)(b * 256 + o)) * 4096 + n0 + n] = v;
    }
}

// ============================================================================
extern "C" void kernel_launch(void* const* d_in, const int* in_sizes, int n_in,
                              void* d_out, int out_size, void* d_ws, size_t ws_size,
                              hipStream_t stream)
{
    const float* x = (const float*)d_in[0];
    const float* sem_w = (const float*)d_in[1];
    const float* sem_b = (const float*)d_in[2];
    const float* q_w = (const float*)d_in[3];
    const float* k_w = (const float*)d_in[4];
    const float* v_w = (const float*)d_in[5];
    const float* fuse_w = (const float*)d_in[6];
    const float* fuse_b = (const float*)d_in[7];
    const float* alpha = (const float*)d_in[8];
    const float* ln_g = (const float*)d_in[9];
    const float* ln_b = (const float*)d_in[10];
    float* out = (float*)d_out;

    char* ws = (char*)d_ws;
    float* Y    = (float*)(ws);              // 13,631,488 B
    float* SP   = (float*)(ws + 13631488);   //  8,388,608 B
    float* P    = (float*)(ws + 22020096);   //  2,621,440 B
    float* REG  = (float*)(ws + 24641536);   //     81,920 B
    int*   HR   = (int*)  (ws + 24723456);   //     32,768 B
    int*   TI   = (int*)  (ws + 24756224);   //     65,536 B
    int*   CNT  = (int*)  (ws + 24821760);   //        256 B
    int*   PLIST= (int*)  (ws + 24822016);   //  1,048,576 B -> total 25,870,592

    proj_kernel<<<dim3(64, 7, 2), 256, 0, stream>>>(x, sem_w, sem_b, q_w, k_w, v_w, Y);
    semsoft_kernel<<<32, 256, 0, stream>>>(Y, HR);
    hipMemsetAsync(CNT, 0, 256, stream);
    bin_kernel<<<32, 256, 0, stream>>>(HR, CNT, PLIST);
    region_partial_kernel<<<dim3(32, 2, 5), 256, 0, stream>>>(Y, P);
    region_reduce_kernel<<<80, 256, 0, stream>>>(P, REG);
    topk_sem_kernel<<<dim3(32, 2), 256, 0, stream>>>(Y, TI);
    sparse_attn_kernel<<<dim3(64, NSUB), 256, 0, stream>>>(Y, CNT, PLIST, TI, SP);
    combine_kernel<<<dim3(128, 2), 256, 0, stream>>>(Y, REG, alpha, SP);
    fuse_ln_kernel<<<dim3(128, 2), 256, 0, stream>>>(SP, fuse_w, fuse_b, x, ln_g, ln_b, out);
}